// Round 10
// baseline (706.133 us; speedup 1.0000x reference)
//
#include <hip/hip_runtime.h>
#include <math.h>

#define EPSF 1e-7f
#define KPAD 1024
#define M_PAD 50176   // 196 * 256
#define NWG2 784      // 196 * 4 = 8 * 98

typedef __attribute__((ext_vector_type(8))) short bf16x8;
typedef __attribute__((ext_vector_type(4))) float f32x4;
typedef __attribute__((ext_vector_type(8))) float f32x8;
typedef __attribute__((ext_vector_type(4))) unsigned short us4;
typedef __attribute__((ext_vector_type(8))) unsigned short us8;

__device__ inline unsigned short f2bf(float f) {
  unsigned u = __float_as_uint(f);
  return (unsigned short)((u + 0x7FFFu + ((u >> 16) & 1u)) >> 16);
}
__device__ inline float bf2f(unsigned short s) {
  return __uint_as_float(((unsigned)s) << 16);
}

__device__ inline void gload_lds16(const void* g, void* l) {
  __builtin_amdgcn_global_load_lds((const __attribute__((address_space(1))) void*)g,
                                   (__attribute__((address_space(3))) void*)l, 16, 0, 0);
}

// ---------- conversions ----------
__global__ __launch_bounds__(256) void cvt_rows_bf16(const float* __restrict__ x,
                                                     unsigned short* __restrict__ o) {
  int i = blockIdx.x, t = threadIdx.x;
  float4 v = *(const float4*)(x + (size_t)i * 1024 + 4 * t);
  us4 u = {f2bf(v.x), f2bf(v.y), f2bf(v.z), f2bf(v.w)};
  *(us4*)(o + (size_t)i * 1024 + 4 * t) = u;
}

__global__ __launch_bounds__(256) void cvt_w_bf16(const float* __restrict__ W,
                                                  unsigned short* __restrict__ o,
                                                  int rows, int cols) {
  int r = blockIdx.x, t = threadIdx.x;
  int c0 = 4 * t;
  us4 u;
#pragma unroll
  for (int j = 0; j < 4; ++j) {
    int c = c0 + j;
    float v = (r < rows && c < cols) ? W[(size_t)r * cols + c] : 0.0f;
    u[j] = f2bf(v);
  }
  *(us4*)(o + (size_t)r * 1024 + c0) = u;
}

// ---------- GEMM 256x256, BK=64, 8-phase double-buffer, counted vmcnt(6) ----------
// (round-7 schedule — empirical best for this shape; byte-identical)
__global__ __launch_bounds__(512, 2) void gemm_bt256(const unsigned short* __restrict__ A,
                                                     const unsigned short* __restrict__ B,
                                                     const float* __restrict__ bias,
                                                     unsigned short* __restrict__ C,
                                                     float* __restrict__ rowss) {
  __shared__ unsigned short lA[2 * 2 * 8192];  // 64 KB
  __shared__ unsigned short lB[2 * 2 * 8192];  // 64 KB
  const int wg = blockIdx.x;
  const int swz = (wg & 7) * 98 + (wg >> 3);  // bijective: 784 = 8*98
  const int bm = swz >> 2, bn = swz & 3;
  const int tid = threadIdx.x;
  const int wave = tid >> 6, lane = tid & 63;
  const int wr = wave >> 2, wc = wave & 3;  // 2 x 4 wave grid, 128x64 per wave
  const int fr = lane & 15, fg = lane >> 4;

  const unsigned short* Abase = A + (size_t)bm * 256 * KPAD;
  const unsigned short* Bbase = B + (size_t)bn * 256 * KPAD;

  const int aHalf = wr * 8192;
  const int bHalf = (wc >> 1) * 8192;
  const int lrB0 = (wc & 1) * 64;
  int ps[2];
#pragma unroll
  for (int s = 0; s < 2; ++s) ps[s] = (((s << 2) + fg) ^ (fr & 7)) << 3;

  const int sRow8 = lane >> 3;
  const int sDst = wave * 512 + lane * 8;
  const int sGran = ((lane & 7) ^ sRow8) << 3;

  f32x4 acc[8][4];
#pragma unroll
  for (int m = 0; m < 8; ++m)
#pragma unroll
    for (int n2 = 0; n2 < 4; ++n2) acc[m][n2] = (f32x4)0.0f;

  bf16x8 af[4][2], bf[4][2];

  auto STAGE_A = [&](int t, int h) {
    const int p = t & 1;
#pragma unroll
    for (int q = 0; q < 2; ++q) {
      int row = h * 128 + q * 64 + wave * 8 + sRow8;
      gload_lds16(Abase + (size_t)row * KPAD + t * 64 + sGran,
                  &lA[p * 16384 + h * 8192 + q * 4096 + sDst]);
    }
  };
  auto STAGE_B = [&](int t, int h) {
    const int p = t & 1;
#pragma unroll
    for (int q = 0; q < 2; ++q) {
      int row = h * 128 + q * 64 + wave * 8 + sRow8;
      gload_lds16(Bbase + (size_t)row * KPAD + t * 64 + sGran,
                  &lB[p * 16384 + h * 8192 + q * 4096 + sDst]);
    }
  };
  auto LDA4 = [&](int p, int mg) {
#pragma unroll
    for (int mi = 0; mi < 4; ++mi) {
      int ro = p * 16384 + aHalf + ((mg * 4 + mi) * 16 + fr) * 64;
#pragma unroll
      for (int s = 0; s < 2; ++s) af[mi][s] = *(const bf16x8*)&lA[ro + ps[s]];
    }
  };
  auto LDB2 = [&](int p, int ng) {
#pragma unroll
    for (int ni = 0; ni < 2; ++ni) {
      int ro = p * 16384 + bHalf + (lrB0 + (ng * 2 + ni) * 16 + fr) * 64;
#pragma unroll
      for (int s = 0; s < 2; ++s) bf[ng * 2 + ni][s] = *(const bf16x8*)&lB[ro + ps[s]];
    }
  };
  auto MM = [&](int mq, int nq) {
    __builtin_amdgcn_s_setprio(1);
#pragma unroll
    for (int mi = 0; mi < 4; ++mi)
#pragma unroll
      for (int ni = 0; ni < 2; ++ni)
#pragma unroll
        for (int s = 0; s < 2; ++s)
          acc[mq * 4 + mi][nq * 2 + ni] = __builtin_amdgcn_mfma_f32_16x16x32_bf16(
              af[mi][s], bf[nq * 2 + ni][s], acc[mq * 4 + mi][nq * 2 + ni], 0, 0, 0);
    __builtin_amdgcn_s_setprio(0);
  };
#define BAR() __builtin_amdgcn_s_barrier()

  STAGE_B(0, 0); STAGE_B(0, 1); STAGE_A(0, 0); STAGE_A(0, 1);
  STAGE_B(1, 0); STAGE_B(1, 1); STAGE_A(1, 0);
  asm volatile("s_waitcnt vmcnt(6)" ::: "memory");
  BAR();

#pragma unroll 1
  for (int it = 0; it < 7; ++it) {
    const int t0 = 2 * it, t1 = t0 + 1;
    LDA4(0, 0); LDB2(0, 0);
    STAGE_A(t1, 1);
    BAR(); MM(0, 0); BAR();
    LDB2(0, 1);
    BAR(); MM(0, 1); BAR();
    LDA4(0, 1);
    STAGE_B(t0 + 2, 0);
    BAR(); MM(1, 0); BAR();
    STAGE_B(t0 + 2, 1); STAGE_A(t0 + 2, 0);
    asm volatile("s_waitcnt vmcnt(6)" ::: "memory");
    BAR(); MM(1, 1); BAR();
    LDA4(1, 0); LDB2(1, 0);
    STAGE_A(t0 + 2, 1);
    BAR(); MM(0, 0); BAR();
    LDB2(1, 1);
    BAR(); MM(0, 1); BAR();
    LDA4(1, 1);
    STAGE_B(t1 + 2, 0);
    BAR(); MM(1, 0); BAR();
    STAGE_B(t1 + 2, 1); STAGE_A(t1 + 2, 0);
    asm volatile("s_waitcnt vmcnt(6)" ::: "memory");
    BAR(); MM(1, 1); BAR();
  }

  asm volatile("s_waitcnt vmcnt(0)" ::: "memory");
  BAR();
#pragma unroll
  for (int p = 0; p < 2; ++p) {
    LDA4(p, 0); LDB2(p, 0); MM(0, 0);
    LDB2(p, 1); MM(0, 1);
    LDA4(p, 1); MM(1, 0); MM(1, 1);
  }
#undef BAR

  // ----- epilogue: bf16 store + per-row sum-of-squares partial -----
  const int crow0 = bm * 256 + wr * 128;
  const int ccol0 = bn * 256 + wc * 64;
  float rs[8][4];
#pragma unroll
  for (int m = 0; m < 8; ++m)
#pragma unroll
    for (int j = 0; j < 4; ++j) rs[m][j] = 0.0f;
#pragma unroll
  for (int m = 0; m < 8; ++m) {
#pragma unroll
    for (int n2 = 0; n2 < 4; ++n2) {
      int col = ccol0 + n2 * 16 + fr;
      float bv = (col < 1023) ? bias[col] : 0.0f;
      int row0 = crow0 + m * 16 + fg * 4;
      unsigned short* cp = C + (size_t)row0 * 1024 + col;
#pragma unroll
      for (int j = 0; j < 4; ++j) {
        float v = acc[m][n2][j] + bv;
        cp[(size_t)j * 1024] = f2bf(v);
        rs[m][j] += v * v;
      }
    }
  }
#pragma unroll
  for (int m = 0; m < 8; ++m)
#pragma unroll
    for (int j = 0; j < 4; ++j) {
      float v = rs[m][j];
      v += __shfl_xor(v, 1);
      v += __shfl_xor(v, 2);
      v += __shfl_xor(v, 4);
      v += __shfl_xor(v, 8);
      rs[m][j] = v;
    }
  __syncthreads();
  float* red = (float*)lA;
  if (fr == 0) {
#pragma unroll
    for (int m = 0; m < 8; ++m)
#pragma unroll
      for (int j = 0; j < 4; ++j)
        red[(wr * 128 + m * 16 + fg * 4 + j) * 4 + wc] = rs[m][j];
  }
  __syncthreads();
  if (tid < 256) {
    float s = red[tid * 4] + red[tid * 4 + 1] + red[tid * 4 + 2] + red[tid * 4 + 3];
    rowss[(size_t)(bm * 256 + tid) * 4 + bn] = s;
  }
}

// ---------- finalize per-row expmap scale from rowss partials ----------
__global__ __launch_bounds__(256) void row_finalize(const float* __restrict__ rowss,
                                                    unsigned short* __restrict__ raw,
                                                    float* __restrict__ sc_tab, float sqrtK,
                                                    int n) {
  int i = blockIdx.x * 256 + threadIdx.x;
  if (i >= n) return;
  float ss = rowss[4 * i] + rowss[4 * i + 1] + rowss[4 * i + 2] + rowss[4 * i + 3];
  float un = fmaxf(sqrtf(ss), EPSF);
  float tt = un / sqrtK;
  float e = expf(tt);
  float ch = 0.5f * (e + 1.0f / e), sh = 0.5f * (e - 1.0f / e);
  float h0 = sqrtK * ch, sc = sqrtK * sh / un;
  sc_tab[i] = sc;
  raw[(size_t)i * 1024 + 1023] = f2bf(h0 / sc);
}

// ---------- per-layer pre-folded edge weights: wedge[j] = w_j * sc[src_j] ----------
__global__ __launch_bounds__(256) void prep_w(const int2* __restrict__ sedge,
                                              const float* __restrict__ sc,
                                              float* __restrict__ wedge, int nE) {
  int i = blockIdx.x * 256 + threadIdx.x;
  if (i < nE) {
    int2 e = sedge[i];
    wedge[i] = __int_as_float(e.y) * sc[e.x];
  }
}

// ---------- CSR build ----------
__global__ __launch_bounds__(256) void deg_count(const int* __restrict__ ed, int* __restrict__ cnt,
                                                 int nE) {
  int i = blockIdx.x * 256 + threadIdx.x;
  if (i < nE) atomicAdd(&cnt[ed[i]], 1);
}

__global__ __launch_bounds__(256) void scan1(const int* __restrict__ cnt, int* __restrict__ excl,
                                             int* __restrict__ bsum, int n) {
  __shared__ int s[256];
  int t = threadIdx.x;
  int i = blockIdx.x * 256 + t;
  int v = (i < n) ? cnt[i] : 0;
  s[t] = v;
  __syncthreads();
#pragma unroll
  for (int o = 1; o < 256; o <<= 1) {
    int add = (t >= o) ? s[t - o] : 0;
    __syncthreads();
    s[t] += add;
    __syncthreads();
  }
  if (i < n) excl[i] = s[t] - v;
  if (t == 255) bsum[blockIdx.x] = s[t];
}

__global__ __launch_bounds__(256) void scan2(int* __restrict__ bsum, int* __restrict__ boff,
                                             int nb) {
  __shared__ int s[256];
  int t = threadIdx.x;
  int v = (t < nb) ? bsum[t] : 0;
  s[t] = v;
  __syncthreads();
#pragma unroll
  for (int o = 1; o < 256; o <<= 1) {
    int add = (t >= o) ? s[t - o] : 0;
    __syncthreads();
    s[t] += add;
    __syncthreads();
  }
  if (t < nb) boff[t] = s[t] - v;
}

__global__ __launch_bounds__(256) void scan3(int* __restrict__ excl, const int* __restrict__ boff,
                                             int* __restrict__ rowstart, int* __restrict__ fill,
                                             int n, int nE) {
  int i = blockIdx.x * 256 + threadIdx.x;
  if (i < n) {
    int v = excl[i] + boff[blockIdx.x];
    rowstart[i] = v;
    fill[i] = v;
  }
  if (i == 0) rowstart[n] = nE;
}

__global__ __launch_bounds__(256) void bucket_fill(const int* __restrict__ es,
                                                   const int* __restrict__ ed,
                                                   const float* __restrict__ ew,
                                                   int* __restrict__ fill,
                                                   int2* __restrict__ sedge, int nE) {
  int i = blockIdx.x * 256 + threadIdx.x;
  if (i < nE) {
    int d = ed[i];
    int pos = atomicAdd(&fill[d], 1);
    sedge[pos] = make_int2(es[i], __float_as_int(ew[i]));
  }
}

// ---------- wave-per-row gather core (pre-folded weights, no sc lookup) ----------
__device__ inline void gather_row_wave(const unsigned short* __restrict__ h,
                                       const int2* __restrict__ sedge,
                                       const float* __restrict__ wedge, int j0, int j1,
                                       int lane, float* fa, float* fb) {
  const char* hb = (const char*)h;
  int j = j0;
  for (; j + 2 <= j1; j += 2) {
    int s0 = sedge[j].x, s1 = sedge[j + 1].x;
    float w0 = wedge[j], w1 = wedge[j + 1];
    const us8* p0 = (const us8*)(hb + (((unsigned)s0) << 11)) + lane;
    const us8* p1 = (const us8*)(hb + (((unsigned)s1) << 11)) + lane;
    us8 a0 = p0[0], b0 = p0[64];
    us8 a1 = p1[0], b1 = p1[64];
#pragma unroll
    for (int q = 0; q < 8; ++q) {
      fa[q] += w0 * bf2f(a0[q]) + w1 * bf2f(a1[q]);
      fb[q] += w0 * bf2f(b0[q]) + w1 * bf2f(b1[q]);
    }
  }
  if (j < j1) {
    int s0 = sedge[j].x;
    float w = wedge[j];
    const us8* p = (const us8*)(hb + (((unsigned)s0) << 11)) + lane;
    us8 a = p[0], b = p[64];
#pragma unroll
    for (int q = 0; q < 8; ++q) {
      fa[q] += w * bf2f(a[q]);
      fb[q] += w * bf2f(b[q]);
    }
  }
}

__device__ inline float wave_sum(float v) {
#pragma unroll
  for (int m = 1; m <= 32; m <<= 1) v += __shfl_xor(v, m);
  return v;
}

// ---------- gather + centroid + logmap0 + relu -> bf16 tangent (layer-1 tail) ----------
__global__ __launch_bounds__(256) void gather_centroid_tangent(
    const unsigned short* __restrict__ h, const int* __restrict__ rs,
    const int2* __restrict__ sedge, const float* __restrict__ wedge,
    unsigned short* __restrict__ u16, float sqrtK, int n) {
  int wv = threadIdx.x >> 6, lane = threadIdx.x & 63;
  int i = blockIdx.x * 4 + wv;
  if (i >= n) return;
  int j0 = rs[i], j1 = rs[i + 1];
  float fa[8] = {0.f, 0.f, 0.f, 0.f, 0.f, 0.f, 0.f, 0.f};
  float fb[8] = {0.f, 0.f, 0.f, 0.f, 0.f, 0.f, 0.f, 0.f};
  gather_row_wave(h, sedge, wedge, j0, j1, lane, fa, fb);
  float m0 = __shfl(fb[7], 63);  // time coord (col 1023)
  if (lane == 63) fb[7] = 0.0f;
  float ssl = 0.f;
#pragma unroll
  for (int q = 0; q < 8; ++q) ssl += fa[q] * fa[q] + fb[q] * fb[q];
  float ss = wave_sum(ssl);

  float l = ss - m0 * m0;
  float denom = sqrtf(fmaxf(fabsf(l), EPSF));
  float c = sqrtK / denom;
  float xn = fmaxf(c * sqrtf(ss), EPSF);
  float theta = fmaxf(m0 / denom, 1.0f + EPSF);
  float d = sqrtK * acoshf(theta);
  float f = c * (d / xn);
  us8 ua, ub;
#pragma unroll
  for (int q = 0; q < 8; ++q) {
    ua[q] = f2bf(fmaxf(fa[q], 0.0f) * f);
    ub[q] = f2bf(fmaxf(fb[q], 0.0f) * f);
  }
  if (lane == 63) ub[7] = 0;  // col 1023 pad
  unsigned short* o = u16 + (size_t)i * 1024 + lane * 8;
  __builtin_nontemporal_store(ua, (us8*)o);
  __builtin_nontemporal_store(ub, (us8*)(o + 512));
}

// ---------- gather + centroid + logmap + relu + expmap + proj -> y (layer-2 tail) ----------
__global__ __launch_bounds__(256) void gather_centroid_final(
    const unsigned short* __restrict__ h, const int* __restrict__ rs,
    const int2* __restrict__ sedge, const float* __restrict__ wedge, float* __restrict__ y,
    float sqrtKin, float sqrtKout, int n) {
  int wv = threadIdx.x >> 6, lane = threadIdx.x & 63;
  int i = blockIdx.x * 4 + wv;
  if (i >= n) return;
  int j0 = rs[i], j1 = rs[i + 1];
  float fa[8] = {0.f, 0.f, 0.f, 0.f, 0.f, 0.f, 0.f, 0.f};
  float fb[8] = {0.f, 0.f, 0.f, 0.f, 0.f, 0.f, 0.f, 0.f};
  gather_row_wave(h, sedge, wedge, j0, j1, lane, fa, fb);
  float m0 = __shfl(fb[7], 63);
  if (lane == 63) fb[7] = 0.0f;
  float ssl = 0.f;
#pragma unroll
  for (int q = 0; q < 8; ++q) ssl += fa[q] * fa[q] + fb[q] * fb[q];
  float ss = wave_sum(ssl);

  float l = ss - m0 * m0;
  float denom = sqrtf(fmaxf(fabsf(l), EPSF));
  float c = sqrtKin / denom;
  float xn = fmaxf(c * sqrtf(ss), EPSF);
  float theta = fmaxf(m0 / denom, 1.0f + EPSF);
  float d = sqrtKin * acoshf(theta);
  float f = c * (d / xn);
  float oa[8], ob[8];
  float ss2l = 0.f;
#pragma unroll
  for (int q = 0; q < 8; ++q) {
    oa[q] = fmaxf(fa[q], 0.0f) * f;
    ob[q] = fmaxf(fb[q], 0.0f) * f;
  }
  if (lane == 63) ob[7] = 0.0f;
#pragma unroll
  for (int q = 0; q < 8; ++q) ss2l += oa[q] * oa[q] + ob[q] * ob[q];
  float ss2 = wave_sum(ss2l);

  float un = fmaxf(sqrtf(ss2), EPSF);
  float tt = un / sqrtKout;
  float e = expf(tt);
  float ch = 0.5f * (e + 1.0f / e), sh = 0.5f * (e - 1.0f / e);
  float y0 = sqrtKout * ch, scale = sqrtKout * sh / un;

  // lane-shift for aligned stores: y[c] = scale*o[c-1], y[0] = y0
  float pa7 = __shfl_up(oa[7], 1);
  float pb7 = __shfl_up(ob[7], 1);
  float a63 = __shfl(oa[7], 63);
  f32x8 va, vb;
  va[0] = (lane == 0) ? y0 : scale * pa7;
  vb[0] = (lane == 0) ? scale * a63 : scale * pb7;
#pragma unroll
  for (int q = 1; q < 8; ++q) {
    va[q] = scale * oa[q - 1];
    vb[q] = scale * ob[q - 1];
  }
  float* yr = y + (size_t)i * 1024;
  __builtin_nontemporal_store(va, (f32x8*)(yr + lane * 8));
  __builtin_nontemporal_store(vb, (f32x8*)(yr + 512 + lane * 8));
}

extern "C" void kernel_launch(void* const* d_in, const int* in_sizes, int n_in,
                              void* d_out, int out_size, void* d_ws, size_t ws_size,
                              hipStream_t stream) {
  const float* x = (const float*)d_in[0];
  const int* es = (const int*)d_in[1];
  const int* ed = (const int*)d_in[2];
  const float* ew = (const float*)d_in[3];
  const float* W1 = (const float*)d_in[4];
  const float* b1 = (const float*)d_in[5];
  const float* W2 = (const float*)d_in[6];
  const float* b2 = (const float*)d_in[7];
  float* y = (float*)d_out;

  const int n = in_sizes[0] / 1024;  // 50000
  const int nE = in_sizes[1];        // 400000
  const int NB = (n + 255) / 256;    // 196
  const int EB = (nE + 255) / 256;

  // workspace layout (offsets 256B-aligned)
  char* ws = (char*)d_ws;
  size_t off = 0;
  auto alloc = [&](size_t bytes) {
    void* p = ws + off;
    off += (bytes + 255) & ~(size_t)255;
    return p;
  };
  unsigned short* u16 = (unsigned short*)alloc((size_t)M_PAD * 1024 * 2);
  unsigned short* w16 = (unsigned short*)alloc((size_t)1024 * 1024 * 2);
  unsigned short* raw16 = (unsigned short*)alloc((size_t)M_PAD * 1024 * 2);
  float* sc_tab = (float*)alloc((size_t)M_PAD * 4);
  float* rowss = (float*)alloc((size_t)M_PAD * 4 * 4);
  int* cnt = (int*)alloc((size_t)(n + 1) * 4);
  int* excl = (int*)alloc((size_t)n * 4);
  int* rowstart = (int*)alloc((size_t)(n + 1) * 4);
  int* fill = (int*)alloc((size_t)n * 4);
  int* bsum = (int*)alloc(256 * 4);
  int* boff = (int*)alloc(256 * 4);
  int2* sedge = (int2*)alloc((size_t)nE * 8);
  float* wedge = (float*)alloc((size_t)nE * 4);

  const float sK1 = 1.0f;                 // sqrt(K_IN)
  const float sK2 = 1.0488088481701516f;  // sqrt(1.1)
  const float sK3 = 1.0954451150103321f;  // sqrt(1.2)

  const int GB = (n + 3) / 4;  // 4 rows (waves) per gather block

  // ----- CSR build (edges shared by both layers) -----
  hipMemsetAsync(cnt, 0, (size_t)(n + 1) * 4, stream);
  deg_count<<<EB, 256, 0, stream>>>(ed, cnt, nE);
  scan1<<<NB, 256, 0, stream>>>(cnt, excl, bsum, n);
  scan2<<<1, 256, 0, stream>>>(bsum, boff, NB);
  scan3<<<NB, 256, 0, stream>>>(excl, boff, rowstart, fill, n, nE);
  bucket_fill<<<EB, 256, 0, stream>>>(es, ed, ew, fill, sedge, nE);

  // ----- layer 1 -----
  cvt_rows_bf16<<<n, 256, 0, stream>>>(x, u16);
  cvt_w_bf16<<<1024, 256, 0, stream>>>(W1, w16, 1023, 1024);
  gemm_bt256<<<NWG2, 512, 0, stream>>>(u16, w16, b1, raw16, rowss);
  row_finalize<<<NB, 256, 0, stream>>>(rowss, raw16, sc_tab, sK1, n);
  prep_w<<<EB, 256, 0, stream>>>(sedge, sc_tab, wedge, nE);
  gather_centroid_tangent<<<GB, 256, 0, stream>>>(raw16, rowstart, sedge, wedge, u16, sK1, n);

  // ----- layer 2 -----
  cvt_w_bf16<<<1024, 256, 0, stream>>>(W2, w16, 1023, 1023);
  gemm_bt256<<<NWG2, 512, 0, stream>>>(u16, w16, b2, raw16, rowss);
  row_finalize<<<NB, 256, 0, stream>>>(rowss, raw16, sc_tab, sK2, n);
  prep_w<<<EB, 256, 0, stream>>>(sedge, sc_tab, wedge, nE);
  gather_centroid_final<<<GB, 256, 0, stream>>>(raw16, rowstart, sedge, wedge, y, sK2, sK3, n);
}

// Round 11
// 685.410 us; speedup vs baseline: 1.0302x; 1.0302x over previous
//
#include <hip/hip_runtime.h>
#include <math.h>

#define EPSF 1e-7f
#define KPAD 1024
#define M_PAD 50176   // 196 * 256
#define NWG2 784      // 196 * 4 = 8 * 98

typedef __attribute__((ext_vector_type(8))) short bf16x8;
typedef __attribute__((ext_vector_type(4))) float f32x4;
typedef __attribute__((ext_vector_type(8))) float f32x8;
typedef __attribute__((ext_vector_type(4))) unsigned short us4;
typedef __attribute__((ext_vector_type(8))) unsigned short us8;

__device__ inline unsigned short f2bf(float f) {
  unsigned u = __float_as_uint(f);
  return (unsigned short)((u + 0x7FFFu + ((u >> 16) & 1u)) >> 16);
}
__device__ inline float bf2f(unsigned short s) {
  return __uint_as_float(((unsigned)s) << 16);
}

__device__ inline void gload_lds16(const void* g, void* l) {
  __builtin_amdgcn_global_load_lds((const __attribute__((address_space(1))) void*)g,
                                   (__attribute__((address_space(3))) void*)l, 16, 0, 0);
}

// ---------- conversions ----------
__global__ __launch_bounds__(256) void cvt_rows_bf16(const float* __restrict__ x,
                                                     unsigned short* __restrict__ o) {
  int i = blockIdx.x, t = threadIdx.x;
  float4 v = *(const float4*)(x + (size_t)i * 1024 + 4 * t);
  us4 u = {f2bf(v.x), f2bf(v.y), f2bf(v.z), f2bf(v.w)};
  *(us4*)(o + (size_t)i * 1024 + 4 * t) = u;
}

__global__ __launch_bounds__(256) void cvt_w_bf16(const float* __restrict__ W,
                                                  unsigned short* __restrict__ o,
                                                  int rows, int cols) {
  int r = blockIdx.x, t = threadIdx.x;
  int c0 = 4 * t;
  us4 u;
#pragma unroll
  for (int j = 0; j < 4; ++j) {
    int c = c0 + j;
    float v = (r < rows && c < cols) ? W[(size_t)r * cols + c] : 0.0f;
    u[j] = f2bf(v);
  }
  *(us4*)(o + (size_t)r * 1024 + c0) = u;
}

// ---------- GEMM 256x256, BK=64, 8-phase double-buffer, counted vmcnt(6) ----------
// (round-7 schedule — empirical best for this shape; byte-identical)
__global__ __launch_bounds__(512, 2) void gemm_bt256(const unsigned short* __restrict__ A,
                                                     const unsigned short* __restrict__ B,
                                                     const float* __restrict__ bias,
                                                     unsigned short* __restrict__ C,
                                                     float* __restrict__ rowss) {
  __shared__ unsigned short lA[2 * 2 * 8192];  // 64 KB
  __shared__ unsigned short lB[2 * 2 * 8192];  // 64 KB
  const int wg = blockIdx.x;
  const int swz = (wg & 7) * 98 + (wg >> 3);  // bijective: 784 = 8*98
  const int bm = swz >> 2, bn = swz & 3;
  const int tid = threadIdx.x;
  const int wave = tid >> 6, lane = tid & 63;
  const int wr = wave >> 2, wc = wave & 3;  // 2 x 4 wave grid, 128x64 per wave
  const int fr = lane & 15, fg = lane >> 4;

  const unsigned short* Abase = A + (size_t)bm * 256 * KPAD;
  const unsigned short* Bbase = B + (size_t)bn * 256 * KPAD;

  const int aHalf = wr * 8192;
  const int bHalf = (wc >> 1) * 8192;
  const int lrB0 = (wc & 1) * 64;
  int ps[2];
#pragma unroll
  for (int s = 0; s < 2; ++s) ps[s] = (((s << 2) + fg) ^ (fr & 7)) << 3;

  const int sRow8 = lane >> 3;
  const int sDst = wave * 512 + lane * 8;
  const int sGran = ((lane & 7) ^ sRow8) << 3;

  f32x4 acc[8][4];
#pragma unroll
  for (int m = 0; m < 8; ++m)
#pragma unroll
    for (int n2 = 0; n2 < 4; ++n2) acc[m][n2] = (f32x4)0.0f;

  bf16x8 af[4][2], bf[4][2];

  auto STAGE_A = [&](int t, int h) {
    const int p = t & 1;
#pragma unroll
    for (int q = 0; q < 2; ++q) {
      int row = h * 128 + q * 64 + wave * 8 + sRow8;
      gload_lds16(Abase + (size_t)row * KPAD + t * 64 + sGran,
                  &lA[p * 16384 + h * 8192 + q * 4096 + sDst]);
    }
  };
  auto STAGE_B = [&](int t, int h) {
    const int p = t & 1;
#pragma unroll
    for (int q = 0; q < 2; ++q) {
      int row = h * 128 + q * 64 + wave * 8 + sRow8;
      gload_lds16(Bbase + (size_t)row * KPAD + t * 64 + sGran,
                  &lB[p * 16384 + h * 8192 + q * 4096 + sDst]);
    }
  };
  auto LDA4 = [&](int p, int mg) {
#pragma unroll
    for (int mi = 0; mi < 4; ++mi) {
      int ro = p * 16384 + aHalf + ((mg * 4 + mi) * 16 + fr) * 64;
#pragma unroll
      for (int s = 0; s < 2; ++s) af[mi][s] = *(const bf16x8*)&lA[ro + ps[s]];
    }
  };
  auto LDB2 = [&](int p, int ng) {
#pragma unroll
    for (int ni = 0; ni < 2; ++ni) {
      int ro = p * 16384 + bHalf + (lrB0 + (ng * 2 + ni) * 16 + fr) * 64;
#pragma unroll
      for (int s = 0; s < 2; ++s) bf[ng * 2 + ni][s] = *(const bf16x8*)&lB[ro + ps[s]];
    }
  };
  auto MM = [&](int mq, int nq) {
    __builtin_amdgcn_s_setprio(1);
#pragma unroll
    for (int mi = 0; mi < 4; ++mi)
#pragma unroll
      for (int ni = 0; ni < 2; ++ni)
#pragma unroll
        for (int s = 0; s < 2; ++s)
          acc[mq * 4 + mi][nq * 2 + ni] = __builtin_amdgcn_mfma_f32_16x16x32_bf16(
              af[mi][s], bf[nq * 2 + ni][s], acc[mq * 4 + mi][nq * 2 + ni], 0, 0, 0);
    __builtin_amdgcn_s_setprio(0);
  };
#define BAR() __builtin_amdgcn_s_barrier()

  STAGE_B(0, 0); STAGE_B(0, 1); STAGE_A(0, 0); STAGE_A(0, 1);
  STAGE_B(1, 0); STAGE_B(1, 1); STAGE_A(1, 0);
  asm volatile("s_waitcnt vmcnt(6)" ::: "memory");
  BAR();

#pragma unroll 1
  for (int it = 0; it < 7; ++it) {
    const int t0 = 2 * it, t1 = t0 + 1;
    LDA4(0, 0); LDB2(0, 0);
    STAGE_A(t1, 1);
    BAR(); MM(0, 0); BAR();
    LDB2(0, 1);
    BAR(); MM(0, 1); BAR();
    LDA4(0, 1);
    STAGE_B(t0 + 2, 0);
    BAR(); MM(1, 0); BAR();
    STAGE_B(t0 + 2, 1); STAGE_A(t0 + 2, 0);
    asm volatile("s_waitcnt vmcnt(6)" ::: "memory");
    BAR(); MM(1, 1); BAR();
    LDA4(1, 0); LDB2(1, 0);
    STAGE_A(t0 + 2, 1);
    BAR(); MM(0, 0); BAR();
    LDB2(1, 1);
    BAR(); MM(0, 1); BAR();
    LDA4(1, 1);
    STAGE_B(t1 + 2, 0);
    BAR(); MM(1, 0); BAR();
    STAGE_B(t1 + 2, 1); STAGE_A(t1 + 2, 0);
    asm volatile("s_waitcnt vmcnt(6)" ::: "memory");
    BAR(); MM(1, 1); BAR();
  }

  asm volatile("s_waitcnt vmcnt(0)" ::: "memory");
  BAR();
#pragma unroll
  for (int p = 0; p < 2; ++p) {
    LDA4(p, 0); LDB2(p, 0); MM(0, 0);
    LDB2(p, 1); MM(0, 1);
    LDA4(p, 1); MM(1, 0); MM(1, 1);
  }
#undef BAR

  // ----- epilogue: bf16 store + per-row sum-of-squares partial -----
  const int crow0 = bm * 256 + wr * 128;
  const int ccol0 = bn * 256 + wc * 64;
  float rs[8][4];
#pragma unroll
  for (int m = 0; m < 8; ++m)
#pragma unroll
    for (int j = 0; j < 4; ++j) rs[m][j] = 0.0f;
#pragma unroll
  for (int m = 0; m < 8; ++m) {
#pragma unroll
    for (int n2 = 0; n2 < 4; ++n2) {
      int col = ccol0 + n2 * 16 + fr;
      float bv = (col < 1023) ? bias[col] : 0.0f;
      int row0 = crow0 + m * 16 + fg * 4;
      unsigned short* cp = C + (size_t)row0 * 1024 + col;
#pragma unroll
      for (int j = 0; j < 4; ++j) {
        float v = acc[m][n2][j] + bv;
        cp[(size_t)j * 1024] = f2bf(v);
        rs[m][j] += v * v;
      }
    }
  }
#pragma unroll
  for (int m = 0; m < 8; ++m)
#pragma unroll
    for (int j = 0; j < 4; ++j) {
      float v = rs[m][j];
      v += __shfl_xor(v, 1);
      v += __shfl_xor(v, 2);
      v += __shfl_xor(v, 4);
      v += __shfl_xor(v, 8);
      rs[m][j] = v;
    }
  __syncthreads();
  float* red = (float*)lA;
  if (fr == 0) {
#pragma unroll
    for (int m = 0; m < 8; ++m)
#pragma unroll
      for (int j = 0; j < 4; ++j)
        red[(wr * 128 + m * 16 + fg * 4 + j) * 4 + wc] = rs[m][j];
  }
  __syncthreads();
  if (tid < 256) {
    float s = red[tid * 4] + red[tid * 4 + 1] + red[tid * 4 + 2] + red[tid * 4 + 3];
    rowss[(size_t)(bm * 256 + tid) * 4 + bn] = s;
  }
}

// ---------- finalize per-row expmap scale from rowss partials ----------
__global__ __launch_bounds__(256) void row_finalize(const float* __restrict__ rowss,
                                                    unsigned short* __restrict__ raw,
                                                    float* __restrict__ sc_tab, float sqrtK,
                                                    int n) {
  int i = blockIdx.x * 256 + threadIdx.x;
  if (i >= n) return;
  float ss = rowss[4 * i] + rowss[4 * i + 1] + rowss[4 * i + 2] + rowss[4 * i + 3];
  float un = fmaxf(sqrtf(ss), EPSF);
  float tt = un / sqrtK;
  float e = expf(tt);
  float ch = 0.5f * (e + 1.0f / e), sh = 0.5f * (e - 1.0f / e);
  float h0 = sqrtK * ch, sc = sqrtK * sh / un;
  sc_tab[i] = sc;
  raw[(size_t)i * 1024 + 1023] = f2bf(h0 / sc);
}

// ---------- CSR build ----------
__global__ __launch_bounds__(256) void deg_count(const int* __restrict__ ed, int* __restrict__ cnt,
                                                 int nE) {
  int i = blockIdx.x * 256 + threadIdx.x;
  if (i < nE) atomicAdd(&cnt[ed[i]], 1);
}

__global__ __launch_bounds__(256) void scan1(const int* __restrict__ cnt, int* __restrict__ excl,
                                             int* __restrict__ bsum, int n) {
  __shared__ int s[256];
  int t = threadIdx.x;
  int i = blockIdx.x * 256 + t;
  int v = (i < n) ? cnt[i] : 0;
  s[t] = v;
  __syncthreads();
#pragma unroll
  for (int o = 1; o < 256; o <<= 1) {
    int add = (t >= o) ? s[t - o] : 0;
    __syncthreads();
    s[t] += add;
    __syncthreads();
  }
  if (i < n) excl[i] = s[t] - v;
  if (t == 255) bsum[blockIdx.x] = s[t];
}

__global__ __launch_bounds__(256) void scan2(int* __restrict__ bsum, int* __restrict__ boff,
                                             int nb) {
  __shared__ int s[256];
  int t = threadIdx.x;
  int v = (t < nb) ? bsum[t] : 0;
  s[t] = v;
  __syncthreads();
#pragma unroll
  for (int o = 1; o < 256; o <<= 1) {
    int add = (t >= o) ? s[t - o] : 0;
    __syncthreads();
    s[t] += add;
    __syncthreads();
  }
  if (t < nb) boff[t] = s[t] - v;
}

__global__ __launch_bounds__(256) void scan3(int* __restrict__ excl, const int* __restrict__ boff,
                                             int* __restrict__ rowstart, int* __restrict__ fill,
                                             int n, int nE) {
  int i = blockIdx.x * 256 + threadIdx.x;
  if (i < n) {
    int v = excl[i] + boff[blockIdx.x];
    rowstart[i] = v;
    fill[i] = v;
  }
  if (i == 0) rowstart[n] = nE;
}

__global__ __launch_bounds__(256) void bucket_fill(const int* __restrict__ es,
                                                   const int* __restrict__ ed,
                                                   const float* __restrict__ ew,
                                                   int* __restrict__ fill,
                                                   int2* __restrict__ sedge, int nE) {
  int i = blockIdx.x * 256 + threadIdx.x;
  if (i < nE) {
    int d = ed[i];
    int pos = atomicAdd(&fill[d], 1);
    sedge[pos] = make_int2(es[i], __float_as_int(ew[i]));
  }
}

// ---------- wave-per-row gather core: lane-preloaded edge records, 4-wide groups ----
// One coalesced int2 load fetches up to 64 edge records; src/w broadcast via shfl.
// Row loads for 4 edges issue concurrently (no per-iteration record-load chain).
__device__ inline void gather_row_wave(const unsigned short* __restrict__ h,
                                       const float* __restrict__ sc,
                                       const int2* __restrict__ sedge, int j0, int j1,
                                       int lane, float* fa, float* fb) {
  const char* hb = (const char*)h;
  const int deg = j1 - j0;
  const int cap = deg < 64 ? deg : 64;
  int2 er = make_int2(0, 0);
  if (lane < cap) er = sedge[j0 + lane];
  int j = 0;
  for (; j + 4 <= cap; j += 4) {
    int s0 = __shfl(er.x, j + 0), s1 = __shfl(er.x, j + 1);
    int s2 = __shfl(er.x, j + 2), s3 = __shfl(er.x, j + 3);
    float w0 = __int_as_float(__shfl(er.y, j + 0)) * sc[s0];
    float w1 = __int_as_float(__shfl(er.y, j + 1)) * sc[s1];
    float w2 = __int_as_float(__shfl(er.y, j + 2)) * sc[s2];
    float w3 = __int_as_float(__shfl(er.y, j + 3)) * sc[s3];
    const us8* p0 = (const us8*)(hb + (((unsigned)s0) << 11)) + lane;
    const us8* p1 = (const us8*)(hb + (((unsigned)s1) << 11)) + lane;
    const us8* p2 = (const us8*)(hb + (((unsigned)s2) << 11)) + lane;
    const us8* p3 = (const us8*)(hb + (((unsigned)s3) << 11)) + lane;
    us8 a0 = p0[0], b0 = p0[64];
    us8 a1 = p1[0], b1 = p1[64];
    us8 a2 = p2[0], b2 = p2[64];
    us8 a3 = p3[0], b3 = p3[64];
#pragma unroll
    for (int q = 0; q < 8; ++q) {
      fa[q] += w0 * bf2f(a0[q]) + w1 * bf2f(a1[q]);
      fb[q] += w0 * bf2f(b0[q]) + w1 * bf2f(b1[q]);
      fa[q] += w2 * bf2f(a2[q]) + w3 * bf2f(a3[q]);
      fb[q] += w2 * bf2f(b2[q]) + w3 * bf2f(b3[q]);
    }
  }
  for (; j < cap; ++j) {
    int s0 = __shfl(er.x, j);
    float w = __int_as_float(__shfl(er.y, j)) * sc[s0];
    const us8* p = (const us8*)(hb + (((unsigned)s0) << 11)) + lane;
    us8 a = p[0], b = p[64];
#pragma unroll
    for (int q = 0; q < 8; ++q) {
      fa[q] += w * bf2f(a[q]);
      fb[q] += w * bf2f(b[q]);
    }
  }
  for (int jj = j0 + 64; jj < j1; ++jj) {  // degree > 64 (essentially never)
    int2 e = sedge[jj];
    float w = __int_as_float(e.y) * sc[e.x];
    const us8* p = (const us8*)(hb + (((unsigned)e.x) << 11)) + lane;
    us8 a = p[0], b = p[64];
#pragma unroll
    for (int q = 0; q < 8; ++q) {
      fa[q] += w * bf2f(a[q]);
      fb[q] += w * bf2f(b[q]);
    }
  }
}

__device__ inline float wave_sum(float v) {
#pragma unroll
  for (int m = 1; m <= 32; m <<= 1) v += __shfl_xor(v, m);
  return v;
}

// ---------- gather + centroid + logmap0 + relu -> bf16 tangent (layer-1 tail) ----------
__global__ __launch_bounds__(256) void gather_centroid_tangent(
    const unsigned short* __restrict__ h, const float* __restrict__ sc,
    const int* __restrict__ rs, const int2* __restrict__ sedge,
    unsigned short* __restrict__ u16, float sqrtK, int n) {
  int wv = threadIdx.x >> 6, lane = threadIdx.x & 63;
  int i = blockIdx.x * 4 + wv;
  if (i >= n) return;
  int j0 = rs[i], j1 = rs[i + 1];
  float fa[8] = {0.f, 0.f, 0.f, 0.f, 0.f, 0.f, 0.f, 0.f};
  float fb[8] = {0.f, 0.f, 0.f, 0.f, 0.f, 0.f, 0.f, 0.f};
  gather_row_wave(h, sc, sedge, j0, j1, lane, fa, fb);
  float m0 = __shfl(fb[7], 63);  // time coord (col 1023)
  if (lane == 63) fb[7] = 0.0f;
  float ssl = 0.f;
#pragma unroll
  for (int q = 0; q < 8; ++q) ssl += fa[q] * fa[q] + fb[q] * fb[q];
  float ss = wave_sum(ssl);

  float l = ss - m0 * m0;
  float denom = sqrtf(fmaxf(fabsf(l), EPSF));
  float c = sqrtK / denom;
  float xn = fmaxf(c * sqrtf(ss), EPSF);
  float theta = fmaxf(m0 / denom, 1.0f + EPSF);
  float d = sqrtK * acoshf(theta);
  float f = c * (d / xn);
  us8 ua, ub;
#pragma unroll
  for (int q = 0; q < 8; ++q) {
    ua[q] = f2bf(fmaxf(fa[q], 0.0f) * f);
    ub[q] = f2bf(fmaxf(fb[q], 0.0f) * f);
  }
  if (lane == 63) ub[7] = 0;  // col 1023 pad
  unsigned short* o = u16 + (size_t)i * 1024 + lane * 8;
  *(us8*)o = ua;
  *(us8*)(o + 512) = ub;
}

// ---------- gather + centroid + logmap + relu + expmap + proj -> y (layer-2 tail) ----------
// ALIGNED y-store: lane l writes y[l*8..l*8+7] and y[512+l*8..+7] via lane-shift.
__global__ __launch_bounds__(256) void gather_centroid_final(
    const unsigned short* __restrict__ h, const float* __restrict__ sc,
    const int* __restrict__ rs, const int2* __restrict__ sedge, float* __restrict__ y,
    float sqrtKin, float sqrtKout, int n) {
  int wv = threadIdx.x >> 6, lane = threadIdx.x & 63;
  int i = blockIdx.x * 4 + wv;
  if (i >= n) return;
  int j0 = rs[i], j1 = rs[i + 1];
  float fa[8] = {0.f, 0.f, 0.f, 0.f, 0.f, 0.f, 0.f, 0.f};
  float fb[8] = {0.f, 0.f, 0.f, 0.f, 0.f, 0.f, 0.f, 0.f};
  gather_row_wave(h, sc, sedge, j0, j1, lane, fa, fb);
  float m0 = __shfl(fb[7], 63);
  if (lane == 63) fb[7] = 0.0f;
  float ssl = 0.f;
#pragma unroll
  for (int q = 0; q < 8; ++q) ssl += fa[q] * fa[q] + fb[q] * fb[q];
  float ss = wave_sum(ssl);

  float l = ss - m0 * m0;
  float denom = sqrtf(fmaxf(fabsf(l), EPSF));
  float c = sqrtKin / denom;
  float xn = fmaxf(c * sqrtf(ss), EPSF);
  float theta = fmaxf(m0 / denom, 1.0f + EPSF);
  float d = sqrtKin * acoshf(theta);
  float f = c * (d / xn);
  float oa[8], ob[8];
  float ss2l = 0.f;
#pragma unroll
  for (int q = 0; q < 8; ++q) {
    oa[q] = fmaxf(fa[q], 0.0f) * f;
    ob[q] = fmaxf(fb[q], 0.0f) * f;
  }
  if (lane == 63) ob[7] = 0.0f;
#pragma unroll
  for (int q = 0; q < 8; ++q) ss2l += oa[q] * oa[q] + ob[q] * ob[q];
  float ss2 = wave_sum(ss2l);

  float un = fmaxf(sqrtf(ss2), EPSF);
  float tt = un / sqrtKout;
  float e = expf(tt);
  float ch = 0.5f * (e + 1.0f / e), sh = 0.5f * (e - 1.0f / e);
  float y0 = sqrtKout * ch, scale = sqrtKout * sh / un;

  float pa7 = __shfl_up(oa[7], 1);
  float pb7 = __shfl_up(ob[7], 1);
  float a63 = __shfl(oa[7], 63);
  f32x8 va, vb;
  va[0] = (lane == 0) ? y0 : scale * pa7;
  vb[0] = (lane == 0) ? scale * a63 : scale * pb7;
#pragma unroll
  for (int q = 1; q < 8; ++q) {
    va[q] = scale * oa[q - 1];
    vb[q] = scale * ob[q - 1];
  }
  float* yr = y + (size_t)i * 1024;
  *(f32x8*)(yr + lane * 8) = va;
  *(f32x8*)(yr + 512 + lane * 8) = vb;
}

extern "C" void kernel_launch(void* const* d_in, const int* in_sizes, int n_in,
                              void* d_out, int out_size, void* d_ws, size_t ws_size,
                              hipStream_t stream) {
  const float* x = (const float*)d_in[0];
  const int* es = (const int*)d_in[1];
  const int* ed = (const int*)d_in[2];
  const float* ew = (const float*)d_in[3];
  const float* W1 = (const float*)d_in[4];
  const float* b1 = (const float*)d_in[5];
  const float* W2 = (const float*)d_in[6];
  const float* b2 = (const float*)d_in[7];
  float* y = (float*)d_out;

  const int n = in_sizes[0] / 1024;  // 50000
  const int nE = in_sizes[1];        // 400000
  const int NB = (n + 255) / 256;    // 196
  const int EB = (nE + 255) / 256;

  // workspace layout (offsets 256B-aligned)
  char* ws = (char*)d_ws;
  size_t off = 0;
  auto alloc = [&](size_t bytes) {
    void* p = ws + off;
    off += (bytes + 255) & ~(size_t)255;
    return p;
  };
  unsigned short* u16 = (unsigned short*)alloc((size_t)M_PAD * 1024 * 2);
  unsigned short* w16 = (unsigned short*)alloc((size_t)1024 * 1024 * 2);
  unsigned short* raw16 = (unsigned short*)alloc((size_t)M_PAD * 1024 * 2);
  float* sc_tab = (float*)alloc((size_t)M_PAD * 4);
  float* rowss = (float*)alloc((size_t)M_PAD * 4 * 4);
  int* cnt = (int*)alloc((size_t)(n + 1) * 4);
  int* excl = (int*)alloc((size_t)n * 4);
  int* rowstart = (int*)alloc((size_t)(n + 1) * 4);
  int* fill = (int*)alloc((size_t)n * 4);
  int* bsum = (int*)alloc(256 * 4);
  int* boff = (int*)alloc(256 * 4);
  int2* sedge = (int2*)alloc((size_t)nE * 8);

  const float sK1 = 1.0f;                 // sqrt(K_IN)
  const float sK2 = 1.0488088481701516f;  // sqrt(1.1)
  const float sK3 = 1.0954451150103321f;  // sqrt(1.2)

  const int GB = (n + 3) / 4;  // 4 rows (waves) per gather block

  // ----- CSR build (edges shared by both layers) -----
  hipMemsetAsync(cnt, 0, (size_t)(n + 1) * 4, stream);
  deg_count<<<EB, 256, 0, stream>>>(ed, cnt, nE);
  scan1<<<NB, 256, 0, stream>>>(cnt, excl, bsum, n);
  scan2<<<1, 256, 0, stream>>>(bsum, boff, NB);
  scan3<<<NB, 256, 0, stream>>>(excl, boff, rowstart, fill, n, nE);
  bucket_fill<<<EB, 256, 0, stream>>>(es, ed, ew, fill, sedge, nE);

  // ----- layer 1 -----
  cvt_rows_bf16<<<n, 256, 0, stream>>>(x, u16);
  cvt_w_bf16<<<1024, 256, 0, stream>>>(W1, w16, 1023, 1024);
  gemm_bt256<<<NWG2, 512, 0, stream>>>(u16, w16, b1, raw16, rowss);
  row_finalize<<<NB, 256, 0, stream>>>(rowss, raw16, sc_tab, sK1, n);
  gather_centroid_tangent<<<GB, 256, 0, stream>>>(raw16, sc_tab, rowstart, sedge, u16, sK1, n);

  // ----- layer 2 -----
  cvt_w_bf16<<<1024, 256, 0, stream>>>(W2, w16, 1023, 1023);
  gemm_bt256<<<NWG2, 512, 0, stream>>>(u16, w16, b2, raw16, rowss);
  row_finalize<<<NB, 256, 0, stream>>>(rowss, raw16, sc_tab, sK2, n);
  gather_centroid_final<<<GB, 256, 0, stream>>>(raw16, sc_tab, rowstart, sedge, y, sK2, sK3, n);
}